// Round 3
// baseline (2458.294 us; speedup 1.0000x reference)
//
#include <hip/hip_runtime.h>
#include <math.h>

#define NN 50000
#define NE 800000

// ---------------------------------------------------------------- utility
__global__ void zero_counts_kernel(int* counts) {
  int i = blockIdx.x * blockDim.x + threadIdx.x;
  if (i < NN) counts[i] = 0;
}

__global__ void count_kernel(const int* __restrict__ dst, int* __restrict__ counts) {
  int e = blockIdx.x * blockDim.x + threadIdx.x;
  if (e < NE) atomicAdd(&counts[dst[e]], 1);
}

// single block, 1024 threads: exclusive scan of counts -> rowptr/cursor,
// plus avg_log = mean(log1p(counts)) -> scal[0]
__global__ void scan_kernel(const int* __restrict__ counts, int* __restrict__ rowptr,
                            int* __restrict__ cursor, float* __restrict__ scal) {
  __shared__ int sdata[1024];
  __shared__ int s_carry;
  __shared__ float wsum[16];
  int t = threadIdx.x;
  if (t == 0) s_carry = 0;
  __syncthreads();
  float logsum = 0.f;
  for (int base = 0; base < NN; base += 1024) {
    int i = base + t;
    int c = (i < NN) ? counts[i] : 0;
    if (i < NN) logsum += log1pf((float)c);
    sdata[t] = c;
    __syncthreads();
    for (int off = 1; off < 1024; off <<= 1) {
      int v = (t >= off) ? sdata[t - off] : 0;
      __syncthreads();
      sdata[t] += v;
      __syncthreads();
    }
    int incl = sdata[t];
    int tot = sdata[1023];
    int excl = incl - c;
    if (i < NN) { int r = s_carry + excl; rowptr[i] = r; cursor[i] = r; }
    __syncthreads();
    if (t == 0) s_carry += tot;
    __syncthreads();
  }
  if (t == 0) rowptr[NN] = s_carry;
  for (int off = 32; off > 0; off >>= 1) logsum += __shfl_down(logsum, off, 64);
  if ((t & 63) == 0) wsum[t >> 6] = logsum;
  __syncthreads();
  if (t == 0) {
    float s = 0.f;
    for (int i = 0; i < 16; i++) s += wsum[i];
    scal[0] = s / (float)NN;
  }
}

__global__ void degs_kernel(const int* __restrict__ counts, const float* __restrict__ scal,
                            float* __restrict__ amp, float* __restrict__ att) {
  int i = blockIdx.x * blockDim.x + threadIdx.x;
  if (i < NN) {
    float deg = fmaxf((float)counts[i], 1.f);
    float ld = logf(deg + 1.f);
    float al = scal[0];
    amp[i] = ld / al;
    att[i] = al / ld;
  }
}

__global__ void scatter_kernel(const int* __restrict__ src, const int* __restrict__ dst,
                               int* __restrict__ cursor, int* __restrict__ ssrc) {
  int e = blockIdx.x * blockDim.x + threadIdx.x;
  if (e < NE) {
    int p = atomicAdd(&cursor[dst[e]], 1);
    ssrc[p] = src[e];
  }
}

// ---------------------------------------------------------------- generic 64-wide GEMM
// C[M,64 slab] = A[M,K] @ W[K,64] (+bias). Tile 64 nodes x 64 cols, 256 threads.
__global__ __launch_bounds__(256) void gemm64_kernel(
    const float* __restrict__ A, int lda, int K,
    const float* __restrict__ W, int ldw,
    const float* __restrict__ bias,
    float* __restrict__ C, int ldc) {
  __shared__ float At[32][68];
  __shared__ float Wt[32][68];
  int t = threadIdx.x;
  int n0 = blockIdx.x * 64;
  int nq = (t >> 4) * 4, cq = (t & 15) * 4;
  float acc[4][4] = {};
  for (int k0 = 0; k0 < K; k0 += 32) {
#pragma unroll
    for (int i = 0; i < 8; i++) {
      int idx = t + i * 256;
      int kl = idx & 31, nl = idx >> 5;
      int row = n0 + nl; if (row >= NN) row = NN - 1;
      At[kl][nl] = A[(size_t)row * lda + k0 + kl];
    }
#pragma unroll
    for (int i = 0; i < 8; i++) {
      int idx = t + i * 256;
      int c = idx & 63, kl = idx >> 6;
      Wt[kl][c] = W[(size_t)(k0 + kl) * ldw + c];
    }
    __syncthreads();
#pragma unroll
    for (int k = 0; k < 32; k++) {
      float4 a = *(const float4*)&At[k][nq];
      float4 w = *(const float4*)&Wt[k][cq];
      float av[4] = {a.x, a.y, a.z, a.w};
      float wv[4] = {w.x, w.y, w.z, w.w};
#pragma unroll
      for (int i = 0; i < 4; i++)
#pragma unroll
        for (int j = 0; j < 4; j++) acc[i][j] += av[i] * wv[j];
    }
    __syncthreads();
  }
#pragma unroll
  for (int i = 0; i < 4; i++) {
    int n = n0 + nq + i;
    if (n < NN) {
#pragma unroll
      for (int j = 0; j < 4; j++) {
        float v = acc[i][j];
        if (bias) v += bias[cq + j];
        C[(size_t)n * ldc + cq + j] = v;
      }
    }
  }
}

// ---------------------------------------------------------------- aggregation
// one wave per node: h_e = pd[n] + ps[src]; accumulate sum/sq/min/max
template <int F>
__global__ __launch_bounds__(256) void agg_kernel(
    const float* __restrict__ pd, const float* __restrict__ ps,
    const int* __restrict__ rowptr, const int* __restrict__ ssrc,
    float* __restrict__ agg) {
  constexpr int C = F / 64;
  int lane = threadIdx.x & 63;
  int wid = threadIdx.x >> 6;
  int n = blockIdx.x * 4 + wid;
  if (n >= NN) return;
  int beg = rowptr[n], end = rowptr[n + 1];
  float pdv[C], sum[C], sq[C], mn[C], mx[C];
#pragma unroll
  for (int c = 0; c < C; c++) {
    pdv[c] = pd[(size_t)n * F + lane + 64 * c];
    sum[c] = 0.f; sq[c] = 0.f; mn[c] = INFINITY; mx[c] = -INFINITY;
  }
  for (int e = beg; e < end; e++) {
    int s = ssrc[e];
#pragma unroll
    for (int c = 0; c < C; c++) {
      float h = pdv[c] + ps[(size_t)s * F + lane + 64 * c];
      sum[c] += h; sq[c] += h * h;
      mn[c] = fminf(mn[c], h); mx[c] = fmaxf(mx[c], h);
    }
  }
  int cnt = end - beg;
  float deg = fmaxf((float)cnt, 1.f);
  float inv = 1.f / deg;
#pragma unroll
  for (int c = 0; c < C; c++) {
    float mean = sum[c] * inv;
    float var = sq[c] * inv - mean * mean;
    float sd = sqrtf(fmaxf(var, 0.f) + 1e-5f);
    float mnv = cnt > 0 ? mn[c] : 0.f;
    float mxv = cnt > 0 ? mx[c] : 0.f;
    size_t b = (size_t)n * 4 * F + lane + 64 * c;
    agg[b] = mean;
    agg[b + F] = mnv;
    agg[b + 2 * F] = mxv;
    agg[b + 3 * F] = sd;
  }
}

// ---------------------------------------------------------------- post NN (fused)
// u = [h_in, agg, amp*agg, att*agg] @ pw + pb ; out = elu(u @ lw + lb + skip)
template <int F>
__global__ __launch_bounds__(256) void post_kernel(
    const float* __restrict__ h_in, const float* __restrict__ agg,
    const float* __restrict__ amp, const float* __restrict__ att,
    const float* __restrict__ pw, const float* __restrict__ pb,
    const float* __restrict__ lw, const float* __restrict__ lb,
    const float* __restrict__ skip, float* __restrict__ out) {
  __shared__ float Xt[32][68];
  __shared__ float Wt[32][68];
  __shared__ float Ut[64][68];
  __shared__ float Lw[64][68];
  __shared__ float s_amp[64], s_att[64];
  int t = threadIdx.x;
  int n0 = blockIdx.x * 64;
#pragma unroll
  for (int i = 0; i < 16; i++) {
    int idx = t + i * 256;
    Lw[idx >> 6][idx & 63] = lw[idx];
  }
  if (t < 64) {
    int n = n0 + t; if (n >= NN) n = NN - 1;
    s_amp[t] = amp[n];
    s_att[t] = att[n];
  }
  __syncthreads();
  int nq = (t >> 4) * 4, cq = (t & 15) * 4;
  float acc[4][4] = {};
  const int KT = 13 * F;
  for (int k0 = 0; k0 < KT; k0 += 32) {
#pragma unroll
    for (int i = 0; i < 8; i++) {
      int idx = t + i * 256;
      int kl = idx & 31, nl = idx >> 5;
      int n = n0 + nl; if (n >= NN) n = NN - 1;
      int kg = k0 + kl;
      float v;
      if (kg < F) v = h_in[(size_t)n * F + kg];
      else if (kg < 5 * F) v = agg[(size_t)n * 4 * F + (kg - F)];
      else if (kg < 9 * F) v = s_amp[nl] * agg[(size_t)n * 4 * F + (kg - 5 * F)];
      else v = s_att[nl] * agg[(size_t)n * 4 * F + (kg - 9 * F)];
      Xt[kl][nl] = v;
    }
#pragma unroll
    for (int i = 0; i < 8; i++) {
      int idx = t + i * 256;
      int c = idx & 63, kl = idx >> 6;
      Wt[kl][c] = pw[(size_t)(k0 + kl) * 64 + c];
    }
    __syncthreads();
#pragma unroll
    for (int k = 0; k < 32; k++) {
      float4 a = *(const float4*)&Xt[k][nq];
      float4 w = *(const float4*)&Wt[k][cq];
      float av[4] = {a.x, a.y, a.z, a.w};
      float wv[4] = {w.x, w.y, w.z, w.w};
#pragma unroll
      for (int i = 0; i < 4; i++)
#pragma unroll
        for (int j = 0; j < 4; j++) acc[i][j] += av[i] * wv[j];
    }
    __syncthreads();
  }
  // u (incl. post bias) -> LDS transposed
#pragma unroll
  for (int i = 0; i < 4; i++)
#pragma unroll
    for (int j = 0; j < 4; j++) Ut[cq + j][nq + i] = acc[i][j] + pb[cq + j];
  __syncthreads();
  float acc2[4][4] = {};
#pragma unroll
  for (int k = 0; k < 64; k++) {
    float4 a = *(const float4*)&Ut[k][nq];
    float4 w = *(const float4*)&Lw[k][cq];
    float av[4] = {a.x, a.y, a.z, a.w};
    float wv[4] = {w.x, w.y, w.z, w.w};
#pragma unroll
    for (int i = 0; i < 4; i++)
#pragma unroll
      for (int j = 0; j < 4; j++) acc2[i][j] += av[i] * wv[j];
  }
#pragma unroll
  for (int i = 0; i < 4; i++) {
    int n = n0 + nq + i;
    if (n < NN) {
#pragma unroll
      for (int j = 0; j < 4; j++) {
        int c = cq + j;
        float v = acc2[i][j] + lb[c] + skip[(size_t)n * 64 + c];
        out[(size_t)n * 64 + c] = v > 0.f ? v : expm1f(v);
      }
    }
  }
}

// ---------------------------------------------------------------- launch
extern "C" void kernel_launch(void* const* d_in, const int* in_sizes, int n_in,
                              void* d_out, int out_size, void* d_ws, size_t ws_size,
                              hipStream_t stream) {
  const float* x = (const float*)d_in[0];
  const int* ei = (const int*)d_in[1];
  const int* esrc = ei;
  const int* edst = ei + NE;
  const float* pre_w[3]  = {(const float*)d_in[2],  (const float*)d_in[8],  (const float*)d_in[14]};
  const float* pre_b[3]  = {(const float*)d_in[3],  (const float*)d_in[9],  (const float*)d_in[15]};
  const float* post_w[3] = {(const float*)d_in[4],  (const float*)d_in[10], (const float*)d_in[16]};
  const float* post_b[3] = {(const float*)d_in[5],  (const float*)d_in[11], (const float*)d_in[17]};
  const float* lin_w[3]  = {(const float*)d_in[6],  (const float*)d_in[12], (const float*)d_in[18]};
  const float* lin_b[3]  = {(const float*)d_in[7],  (const float*)d_in[13], (const float*)d_in[19]};
  const float* skip_w = (const float*)d_in[20];
  const float* skip_b = (const float*)d_in[21];

  char* p = (char*)d_ws;
  auto alloc = [&](size_t b) { char* r = p; p += (b + 255) & ~(size_t)255; return r; };
  int* counts  = (int*)alloc((size_t)NN * 4);
  int* rowptr  = (int*)alloc((size_t)(NN + 1) * 4);
  int* cursor  = (int*)alloc((size_t)NN * 4);
  int* ssrc    = (int*)alloc((size_t)NE * 4);
  float* amp   = (float*)alloc((size_t)NN * 4);
  float* att   = (float*)alloc((size_t)NN * 4);
  float* scal  = (float*)alloc(256);
  float* pd    = (float*)alloc((size_t)NN * 128 * 4);
  float* ps    = (float*)alloc((size_t)NN * 128 * 4);
  float* agg   = (float*)alloc((size_t)NN * 512 * 4);
  float* ha    = (float*)alloc((size_t)NN * 64 * 4);
  float* hb    = (float*)alloc((size_t)NN * 64 * 4);
  float* sk    = (float*)alloc((size_t)NN * 64 * 4);
  (void)ws_size; (void)in_sizes; (void)n_in; (void)out_size;

  zero_counts_kernel<<<(NN + 255) / 256, 256, 0, stream>>>(counts);
  count_kernel<<<(NE + 255) / 256, 256, 0, stream>>>(edst, counts);
  scan_kernel<<<1, 1024, 0, stream>>>(counts, rowptr, cursor, scal);
  degs_kernel<<<(NN + 255) / 256, 256, 0, stream>>>(counts, scal, amp, att);
  scatter_kernel<<<(NE + 255) / 256, 256, 0, stream>>>(esrc, edst, cursor, ssrc);

  int gn = (NN + 63) / 64;

  // skip = x @ skip_w + skip_b
  gemm64_kernel<<<gn, 256, 0, stream>>>(x, 128, 128, skip_w, 64, skip_b, sk, 64);

  // ---- layer 0 (F = 128)
  gemm64_kernel<<<gn, 256, 0, stream>>>(x, 128, 128, pre_w[0],           128, pre_b[0],      pd,      128);
  gemm64_kernel<<<gn, 256, 0, stream>>>(x, 128, 128, pre_w[0] + 64,      128, pre_b[0] + 64, pd + 64, 128);
  gemm64_kernel<<<gn, 256, 0, stream>>>(x, 128, 128, pre_w[0] + 128*128,      128, nullptr,  ps,      128);
  gemm64_kernel<<<gn, 256, 0, stream>>>(x, 128, 128, pre_w[0] + 128*128 + 64, 128, nullptr,  ps + 64, 128);
  agg_kernel<128><<<(NN + 3) / 4, 256, 0, stream>>>(pd, ps, rowptr, ssrc, agg);
  post_kernel<128><<<gn, 256, 0, stream>>>(x, agg, amp, att, post_w[0], post_b[0],
                                           lin_w[0], lin_b[0], sk, ha);

  // ---- layer 1 (F = 64)
  gemm64_kernel<<<gn, 256, 0, stream>>>(ha, 64, 64, pre_w[1],         64, pre_b[1], pd, 64);
  gemm64_kernel<<<gn, 256, 0, stream>>>(ha, 64, 64, pre_w[1] + 64*64, 64, nullptr,  ps, 64);
  agg_kernel<64><<<(NN + 3) / 4, 256, 0, stream>>>(pd, ps, rowptr, ssrc, agg);
  post_kernel<64><<<gn, 256, 0, stream>>>(ha, agg, amp, att, post_w[1], post_b[1],
                                          lin_w[1], lin_b[1], ha, hb);

  // ---- layer 2 (F = 64)
  gemm64_kernel<<<gn, 256, 0, stream>>>(hb, 64, 64, pre_w[2],         64, pre_b[2], pd, 64);
  gemm64_kernel<<<gn, 256, 0, stream>>>(hb, 64, 64, pre_w[2] + 64*64, 64, nullptr,  ps, 64);
  agg_kernel<64><<<(NN + 3) / 4, 256, 0, stream>>>(pd, ps, rowptr, ssrc, agg);
  post_kernel<64><<<gn, 256, 0, stream>>>(hb, agg, amp, att, post_w[2], post_b[2],
                                          lin_w[2], lin_b[2], hb, (float*)d_out);
}